// Round 6
// baseline (369.505 us; speedup 1.0000x reference)
//
#include <hip/hip_runtime.h>

#define NINST 100
#define MLOG 28
#define IMG 800
#define LOGSZ (MLOG * MLOG) /* 784 */

// ws layout (32-bit words):
//  [0..99]    order (original index of n-th highest cls_prob)
//  [100..199] cls (0-based class of ordered instance)
//  [200..599] box (x0,y0,x1,y1 per ordered instance, int-truncated)
//  [600..699] msum
//  [800..899] slot_n (ordered-instance index for output slot s)
//  [900]      nkeep
//  [1024..]   bit-packed masks, stride 3648 words (12 x 304 rows), word col
//             aligned to GLOBAL word grid (word = x/32) so AND needs no shift.
#define OFF_ORDER 0
#define OFF_CLS   100
#define OFF_BOX   200
#define OFF_MSUM  600
#define OFF_SLOT  800
#define OFF_NK    900
#define OFF_MASK  1024
#define ROWW      12
#define MSTRIDE   (ROWW * 304)
#define PCAP      256
#define F4TOT     (NINST * IMG * IMG / 4) /* 16,000,000 float4 of mask_energy */
#define NZBLK     (F4TOT / 256)           /* 62500 zero blocks, 1 float4/thread */

// Blocks [0,100): rank (redundant, from LDS) + rasterize bit-masks + msum.
// Blocks [100, 100+NZBLK): stream zeros over the whole mask_energy output —
// overlapping the 256 MB zero with raster keeps it OFF the post-scan path
// (R5 showed tail placement costs ~38 us).
__global__ __launch_bounds__(256) void k_mask_zero(const float* __restrict__ mask_prob,
                                                   const float* __restrict__ cls_prob,
                                                   const float* __restrict__ rois,
                                                   const int* __restrict__ cls_idx,
                                                   int* __restrict__ ws,
                                                   float* __restrict__ out) {
    int b = blockIdx.x, tid = threadIdx.x;
    if (b >= NINST) { // zero path
        size_t pi = (size_t)(b - NINST) * 256 + tid;
        ((float4*)(out + NINST))[pi] = make_float4(0.f, 0.f, 0.f, 0.f);
        return;
    }
    __shared__ float s_p[NINST];
    __shared__ int s_order[NINST];
    __shared__ float lg[LOGSZ];
    __shared__ int red[256];
    if (tid < NINST) s_p[tid] = cls_prob[tid];
    __syncthreads();
    if (tid < NINST) {
        float p = s_p[tid];
        int r = 0;
        for (int j = 0; j < NINST; j++) {
            float q = s_p[j];
            r += (q > p) || (q == p && j < tid); // stable argsort(-cls_prob)
        }
        s_order[r] = tid;
    }
    __syncthreads();
    int n = b;
    int orig = s_order[n];
    int x0 = (int)rois[4 * orig], y0 = (int)rois[4 * orig + 1];
    int x1 = (int)rois[4 * orig + 2], y1 = (int)rois[4 * orig + 3];
    if (b == 0 && tid < NINST) { // publish metadata for k_scan64 / k_box
        int o = s_order[tid];
        ws[OFF_ORDER + tid] = o;
        ws[OFF_CLS + tid] = cls_idx[o] - 1;
#pragma unroll
        for (int k = 0; k < 4; k++)
            ws[OFF_BOX + 4 * tid + k] = (int)rois[4 * o + k]; // trunc == astype(int32)
    }
    for (int i = tid; i < LOGSZ; i += 256) lg[i] = mask_prob[orig * LOGSZ + i];
    __syncthreads();
    int xs = max(x0, 0), xe = min(x1 + 1, IMG);
    int ys = max(y0, 0), ye = min(y1 + 1, IMG);
    int wx0 = xs >> 5, nw = ((xe + 31) >> 5) - wx0, nrows = ye - ys;
    float wf = fmaxf((float)(x1 - x0 + 1), 1.f), hf = fmaxf((float)(y1 - y0 + 1), 1.f);
    float rx = 28.f / wf, ry = 28.f / hf;
    unsigned* mb = (unsigned*)(ws + OFF_MASK) + n * MSTRIDE;
    int total = nrows * nw, cnt = 0;
    for (int t = tid; t < total; t += 256) {
        int row = t / nw, wc = t - row * nw;
        int y = ys + row;
        float sy = ((float)y - (float)y0 + 0.5f) * ry - 0.5f;
        sy = fminf(fmaxf(sy, 0.f), 27.f);
        int iy0 = (int)sy, iy1 = min(iy0 + 1, 27);
        float fy = sy - (float)iy0;
        const float* r0 = lg + iy0 * MLOG;
        const float* r1 = lg + iy1 * MLOG;
        unsigned bits = 0u;
        int xbase = (wx0 + wc) << 5;
        int j0 = max(xs - xbase, 0), j1 = min(xe - xbase, 32);
        for (int j = j0; j < j1; j++) {
            int xx = xbase + j;
            float sx = ((float)xx - (float)x0 + 0.5f) * rx - 0.5f;
            sx = fminf(fmaxf(sx, 0.f), 27.f);
            int ix0 = (int)sx, ix1 = min(ix0 + 1, 27);
            float fx = sx - (float)ix0;
            float val = (1.f - fy) * ((1.f - fx) * r0[ix0] + fx * r0[ix1]) +
                        fy * ((1.f - fx) * r1[ix0] + fx * r1[ix1]);
            bits |= (val > 0.f) ? (1u << j) : 0u;
        }
        mb[row * ROWW + wc] = bits;
        cnt += __popc(bits);
    }
    red[tid] = cnt;
    __syncthreads();
    for (int s = 128; s; s >>= 1) {
        if (tid < s) red[tid] += red[tid + s];
        __syncthreads();
    }
    if (tid == 0) ws[OFF_MSUM + n] = red[0];
}

__device__ __forceinline__ bool box_ovl(const int* sb, int a, int b2) {
    int axs = max(sb[4 * a], 0), axe = min(sb[4 * a + 2] + 1, IMG);
    int ays = max(sb[4 * a + 1], 0), aye = min(sb[4 * a + 3] + 1, IMG);
    int bxs = max(sb[4 * b2], 0), bxe = min(sb[4 * b2 + 2] + 1, IMG);
    int bys = max(sb[4 * b2 + 1], 0), bye = min(sb[4 * b2 + 3] + 1, IMG);
    return axs < bxe && bxs < axe && ays < bye && bys < aye;
}

// ONE WAVE, no barriers in the hot loop: pair enumeration + popcounts in the
// prologue, then a 100-step scan with keep-bits in uniform register masks.
// Union bounded by max_pair <= |U| <= sum_pair (ints exact in fp32 -> decision
// exact when bounds agree; single candidate always exact). Rare ambiguous
// case: wave-cooperative exact union popcount.
__global__ __launch_bounds__(64) void k_scan64(int* __restrict__ ws, float* __restrict__ out) {
    int ln = threadIdx.x;
    __shared__ int s_cls[NINST], s_msum[NINST], s_box[4 * NINST];
    __shared__ int s_pi[PCAP], s_pj[PCAP], s_po[PCAP];
    __shared__ int s_np;
    for (int i = ln; i < NINST; i += 64) {
        s_cls[i] = ws[OFF_CLS + i];
        s_msum[i] = ws[OFF_MSUM + i];
    }
    for (int i = ln; i < 4 * NINST; i += 64) s_box[i] = ws[OFF_BOX + i];
    if (ln == 0) s_np = 0;
    const unsigned* maskbase = (const unsigned*)(ws + OFF_MASK);
    __syncthreads();

    // pair filter: same class, both non-empty, boxes overlap
    for (int i = 0; i < NINST - 1; i++)
        for (int j = i + 1 + ln; j < NINST; j += 64) {
            if (s_cls[i] != s_cls[j] || !s_msum[i] || !s_msum[j]) continue;
            if (!box_ovl(s_box, i, j)) continue;
            int k = atomicAdd(&s_np, 1);
            if (k < PCAP) { s_pi[k] = i; s_pj[k] = j; }
        }
    __syncthreads();
    int np = min(s_np, PCAP);
    bool pov = (s_np > PCAP);
    // wave-cooperative popcount per pair
    for (int q = 0; q < np; q++) {
        int i = s_pi[q], j = s_pj[q];
        int ixs = max(s_box[4 * i], 0), ixe = min(s_box[4 * i + 2] + 1, IMG);
        int iys = max(s_box[4 * i + 1], 0);
        int jxs = max(s_box[4 * j], 0), jxe = min(s_box[4 * j + 2] + 1, IMG);
        int jys = max(s_box[4 * j + 1], 0);
        int iye = min(s_box[4 * i + 3] + 1, IMG), jye = min(s_box[4 * j + 3] + 1, IMG);
        int iwx0 = ixs >> 5, jwx0 = jxs >> 5;
        int wlo = max(iwx0, jwx0);
        int whi = min((ixe + 31) >> 5, (jxe + 31) >> 5);
        int rlo = max(iys, jys), rhi = min(iye, jye);
        int nw = whi - wlo, nrows = rhi - rlo;
        const unsigned* mi = maskbase + i * MSTRIDE;
        const unsigned* mj = maskbase + j * MSTRIDE;
        int total = nrows * nw, cnt = 0;
        for (int t = ln; t < total; t += 64) {
            int row = t / nw, wc = t - row * nw;
            int y = rlo + row, w = wlo + wc;
            cnt += __popc(mi[(y - iys) * ROWW + (w - iwx0)] &
                          mj[(y - jys) * ROWW + (w - jwx0)]);
        }
        for (int off = 32; off; off >>= 1) cnt += __shfl_down(cnt, off);
        if (ln == 0) s_po[q] = cnt;
    }
    __syncthreads();

    // sequential scan; lane ln owns predecessors ln and 64+ln
    unsigned long long k0 = 0ull, k1 = 0ull;
    for (int n = 0; n < NINST; n++) {
        int pa = ln, pb = 64 + ln;
        bool ca = (pa < n) && s_cls[pa] == s_cls[n] && ((k0 >> ln) & 1ull) && box_ovl(s_box, pa, n);
        bool cb = (pb < n) && s_cls[pb] == s_cls[n] && ((k1 >> ln) & 1ull) && box_ovl(s_box, pb, n);
        int oa = 0, ob = 0;
        if (!pov) {
            if (ca) for (int q = 0; q < np; q++) if (s_pi[q] == pa && s_pj[q] == n) oa = s_po[q];
            if (cb) for (int q = 0; q < np; q++) if (s_pi[q] == pb && s_pj[q] == n) ob = s_po[q];
        }
        int sum = oa + ob, mx = max(oa, ob);
        for (int off = 32; off; off >>= 1) {
            sum += __shfl_down(sum, off);
            mx = max(mx, __shfl_down(mx, off));
        }
        unsigned long long anyc = __ballot(ca || cb);
        int keep = 0, need = 0;
        if (ln == 0) {
            int msum = s_msum[n];
            float t = 0.3f * (float)msum;
            if (pov) need = (anyc != 0ull) ? 1 : 0, keep = (!need && msum > 0);
            else if ((float)sum <= t) keep = (msum > 0);
            else if ((float)mx > t) keep = 0;
            else need = 1; // max <= t < sum: exact union required
        }
        keep = __shfl(keep, 0);
        need = __shfl(need, 0);
        if (need) { // wave-cooperative exact union popcount
            unsigned long long ba = __ballot(ca), bb = __ballot(cb);
            int nxs = max(s_box[4 * n], 0), nxe = min(s_box[4 * n + 2] + 1, IMG);
            int nys = max(s_box[4 * n + 1], 0), nye = min(s_box[4 * n + 3] + 1, IMG);
            int wx0 = nxs >> 5, nw = ((nxe + 31) >> 5) - wx0, nrows = nye - nys;
            const unsigned* mn = maskbase + n * MSTRIDE;
            int total = nrows * nw, ovl = 0;
            for (int t2 = ln; t2 < total; t2 += 64) {
                int row = t2 / nw, wc = t2 - row * nw;
                unsigned bits = mn[row * ROWW + wc];
                if (!bits) continue;
                int y = nys + row, wa = wx0 + wc;
                unsigned img = 0;
                unsigned long long rem = ba;
                while (rem) {
                    int m = __ffsll((long long)rem) - 1; rem &= rem - 1;
                    int mys = max(s_box[4 * m + 1], 0), mye = min(s_box[4 * m + 3] + 1, IMG);
                    int mxs = max(s_box[4 * m], 0), mxe = min(s_box[4 * m + 2] + 1, IMG);
                    int mwx0 = mxs >> 5, mnw = ((mxe + 31) >> 5) - mwx0;
                    int rr = y - mys, cc = wa - mwx0;
                    if (rr >= 0 && rr < (mye - mys) && cc >= 0 && cc < mnw)
                        img |= maskbase[m * MSTRIDE + rr * ROWW + cc];
                }
                rem = bb;
                while (rem) {
                    int m0 = __ffsll((long long)rem) - 1; rem &= rem - 1;
                    int m = 64 + m0;
                    int mys = max(s_box[4 * m + 1], 0), mye = min(s_box[4 * m + 3] + 1, IMG);
                    int mxs = max(s_box[4 * m], 0), mxe = min(s_box[4 * m + 2] + 1, IMG);
                    int mwx0 = mxs >> 5, mnw = ((mxe + 31) >> 5) - mwx0;
                    int rr = y - mys, cc = wa - mwx0;
                    if (rr >= 0 && rr < (mye - mys) && cc >= 0 && cc < mnw)
                        img |= maskbase[m * MSTRIDE + rr * ROWW + cc];
                }
                ovl += __popc(bits & img);
            }
            for (int off = 32; off; off >>= 1) ovl += __shfl_down(ovl, off);
            if (ln == 0) {
                int msum = s_msum[n];
                keep = (msum > 0) && ((float)ovl <= 0.3f * (float)msum);
            }
            keep = __shfl(keep, 0);
        }
        if (keep) { // uniform update of replicated keep masks
            if (n < 64) k0 |= 1ull << n;
            else k1 |= 1ull << (n - 64);
        }
    }

    // epilogue: slots + keep_inds (position = popcount of earlier keep bits)
    int nk = __popcll(k0) + __popcll(k1);
    if (ln == 0) ws[OFF_NK] = nk;
    unsigned long long lm = (ln == 0) ? 0ull : (~0ull >> (64 - ln));
    if ((k0 >> ln) & 1ull) {
        int pos = __popcll(k0 & lm);
        ws[OFF_SLOT + pos] = ln;
        out[pos] = (float)ws[OFF_ORDER + ln];
    }
    if (ln < 36 && ((k1 >> ln) & 1ull)) {
        int pos = __popcll(k0) + __popcll(k1 & lm);
        ws[OFF_SLOT + pos] = 64 + ln;
        out[pos] = (float)ws[OFF_ORDER + 64 + ln];
    }
    for (int s = ln; s < NINST; s += 64)
        if (s >= nk) out[s] = -1.f;
}

// Writes kept boxes' interiors only (~33 MB; rest already zeroed).
__global__ __launch_bounds__(256) void k_box(const float* __restrict__ mask_prob,
                                             const int* __restrict__ ws,
                                             float* __restrict__ out) {
    int slot = blockIdx.y, tid = threadIdx.x;
    if (slot >= ws[OFF_NK]) return; // uniform per block
    int n = ws[OFF_SLOT + slot];
    const int* box = ws + OFF_BOX + 4 * n;
    int x0 = box[0], y0 = box[1], x1 = box[2], y1 = box[3];
    int xs = max(x0, 0), xe = min(x1 + 1, IMG);
    int ys = max(y0, 0), ye = min(y1 + 1, IMG);
    int xa = xs & ~3;
    int w4 = (xe - xa + 3) >> 2;
    int rows = ye - ys;
    int total4 = rows * w4;
    __shared__ float lg[LOGSZ];
    int orig = ws[OFF_ORDER + n];
    for (int i = tid; i < LOGSZ; i += 256) lg[i] = mask_prob[orig * LOGSZ + i];
    __syncthreads();
    float wf = fmaxf((float)(x1 - x0 + 1), 1.f), hf = fmaxf((float)(y1 - y0 + 1), 1.f);
    float rx = 28.f / wf, ry = 28.f / hf;
    float* base = out + NINST + (size_t)slot * (IMG * IMG);
    for (int t = blockIdx.x * 256 + tid; t < total4; t += gridDim.x * 256) {
        int row = t / w4, c4 = t - row * w4;
        int y = ys + row, xb = xa + (c4 << 2);
        float sy = ((float)y - (float)y0 + 0.5f) * ry - 0.5f;
        sy = fminf(fmaxf(sy, 0.f), 27.f);
        int iy0 = (int)sy, iy1 = min(iy0 + 1, 27);
        float fy = sy - (float)iy0;
        const float* r0 = lg + iy0 * MLOG;
        const float* r1 = lg + iy1 * MLOG;
        float v[4];
#pragma unroll
        for (int j = 0; j < 4; j++) {
            int xx = xb + j;
            float val = 0.f;
            if (xx >= xs && xx < xe) {
                float sx = ((float)xx - (float)x0 + 0.5f) * rx - 0.5f;
                sx = fminf(fmaxf(sx, 0.f), 27.f);
                int ix0 = (int)sx, ix1 = min(ix0 + 1, 27);
                float fx = sx - (float)ix0;
                val = (1.f - fy) * ((1.f - fx) * r0[ix0] + fx * r0[ix1]) +
                      fy * ((1.f - fx) * r1[ix0] + fx * r1[ix1]);
            }
            v[j] = val;
        }
        *(float4*)(base + (size_t)y * IMG + xb) = make_float4(v[0], v[1], v[2], v[3]);
    }
}

extern "C" void kernel_launch(void* const* d_in, const int* in_sizes, int n_in,
                              void* d_out, int out_size, void* d_ws, size_t ws_size,
                              hipStream_t stream) {
    const float* rois      = (const float*)d_in[0];
    const float* cls_prob  = (const float*)d_in[1];
    const float* mask_prob = (const float*)d_in[2];
    const int*   cls_idx   = (const int*)d_in[3];
    int* ws = (int*)d_ws;
    float* out = (float*)d_out;

    k_mask_zero<<<dim3(NINST + NZBLK), dim3(256), 0, stream>>>(mask_prob, cls_prob, rois, cls_idx, ws, out);
    k_scan64<<<dim3(1), dim3(64), 0, stream>>>(ws, out);
    // max box 301x301 -> rows*w4 <= 301*77 = 23177 <= 91*256
    k_box<<<dim3(91, NINST), dim3(256), 0, stream>>>(mask_prob, ws, out);
}

// Round 7
// 357.090 us; speedup vs baseline: 1.0348x; 1.0348x over previous
//
#include <hip/hip_runtime.h>

#define NINST 100
#define MLOG 28
#define IMG 800
#define LOGSZ (MLOG * MLOG) /* 784 */

// ws layout (32-bit words):
//  [0..99]    order (original index of n-th highest cls_prob)
//  [100..199] cls (0-based class of ordered instance)
//  [200..599] box (x0,y0,x1,y1 per ordered instance, int-truncated)
//  [600..699] msum
//  [800..899] slot_n (ordered-instance index for output slot s)
//  [900]      nkeep
//  [1024..11023] dense pair-overlap table ovl[i*100+j] (i<j). NOT zeroed:
//             scan reads entry (i,n) only under exactly the conditions
//             k_pairs writes it (same cls, both msum>0, box overlap).
//  [11264..]  bit-packed masks, stride 3648 words (12 x 304 rows), word col
//             aligned to GLOBAL word grid (word = x/32) so AND needs no shift.
#define OFF_ORDER 0
#define OFF_CLS   100
#define OFF_BOX   200
#define OFF_MSUM  600
#define OFF_SLOT  800
#define OFF_NK    900
#define OFF_OVL   1024
#define OFF_MASK  11264
#define ROWW      12
#define MSTRIDE   (ROWW * 304)
#define F4TOT     (NINST * IMG * IMG / 4) /* 16,000,000 float4 of mask_energy */
#define NZB       4096                    /* zero blocks in k_scan_zero */

__device__ __forceinline__ bool box_ovl(const int* sb, int a, int b2) {
    int axs = max(sb[4 * a], 0), axe = min(sb[4 * a + 2] + 1, IMG);
    int ays = max(sb[4 * a + 1], 0), aye = min(sb[4 * a + 3] + 1, IMG);
    int bxs = max(sb[4 * b2], 0), bxe = min(sb[4 * b2 + 2] + 1, IMG);
    int bys = max(sb[4 * b2 + 1], 0), bye = min(sb[4 * b2 + 3] + 1, IMG);
    return axs < bxe && bxs < axe && ays < bye && bys < aye;
}

// Blocks [0,100): rank (redundant, from LDS) + rasterize bit-masks + msum.
__global__ __launch_bounds__(256) void k_mask(const float* __restrict__ mask_prob,
                                              const float* __restrict__ cls_prob,
                                              const float* __restrict__ rois,
                                              const int* __restrict__ cls_idx,
                                              int* __restrict__ ws) {
    int b = blockIdx.x, tid = threadIdx.x;
    __shared__ float s_p[NINST];
    __shared__ int s_order[NINST];
    __shared__ float lg[LOGSZ];
    __shared__ int red[256];
    if (tid < NINST) s_p[tid] = cls_prob[tid];
    __syncthreads();
    if (tid < NINST) {
        float p = s_p[tid];
        int r = 0;
        for (int j = 0; j < NINST; j++) {
            float q = s_p[j];
            r += (q > p) || (q == p && j < tid); // stable argsort(-cls_prob)
        }
        s_order[r] = tid;
    }
    __syncthreads();
    int n = b;
    int orig = s_order[n];
    int x0 = (int)rois[4 * orig], y0 = (int)rois[4 * orig + 1];
    int x1 = (int)rois[4 * orig + 2], y1 = (int)rois[4 * orig + 3];
    if (b == 0 && tid < NINST) { // publish metadata for downstream kernels
        int o = s_order[tid];
        ws[OFF_ORDER + tid] = o;
        ws[OFF_CLS + tid] = cls_idx[o] - 1;
#pragma unroll
        for (int k = 0; k < 4; k++)
            ws[OFF_BOX + 4 * tid + k] = (int)rois[4 * o + k]; // trunc == astype(int32)
    }
    for (int i = tid; i < LOGSZ; i += 256) lg[i] = mask_prob[orig * LOGSZ + i];
    __syncthreads();
    int xs = max(x0, 0), xe = min(x1 + 1, IMG);
    int ys = max(y0, 0), ye = min(y1 + 1, IMG);
    int wx0 = xs >> 5, nw = ((xe + 31) >> 5) - wx0, nrows = ye - ys;
    float wf = fmaxf((float)(x1 - x0 + 1), 1.f), hf = fmaxf((float)(y1 - y0 + 1), 1.f);
    float rx = 28.f / wf, ry = 28.f / hf;
    unsigned* mb = (unsigned*)(ws + OFF_MASK) + n * MSTRIDE;
    int total = nrows * nw, cnt = 0;
    for (int t = tid; t < total; t += 256) {
        int row = t / nw, wc = t - row * nw;
        int y = ys + row;
        float sy = ((float)y - (float)y0 + 0.5f) * ry - 0.5f;
        sy = fminf(fmaxf(sy, 0.f), 27.f);
        int iy0 = (int)sy, iy1 = min(iy0 + 1, 27);
        float fy = sy - (float)iy0;
        const float* r0 = lg + iy0 * MLOG;
        const float* r1 = lg + iy1 * MLOG;
        unsigned bits = 0u;
        int xbase = (wx0 + wc) << 5;
        int j0 = max(xs - xbase, 0), j1 = min(xe - xbase, 32);
        for (int j = j0; j < j1; j++) {
            int xx = xbase + j;
            float sx = ((float)xx - (float)x0 + 0.5f) * rx - 0.5f;
            sx = fminf(fmaxf(sx, 0.f), 27.f);
            int ix0 = (int)sx, ix1 = min(ix0 + 1, 27);
            float fx = sx - (float)ix0;
            float val = (1.f - fy) * ((1.f - fx) * r0[ix0] + fx * r0[ix1]) +
                        fy * ((1.f - fx) * r1[ix0] + fx * r1[ix1]);
            bits |= (val > 0.f) ? (1u << j) : 0u;
        }
        mb[row * ROWW + wc] = bits;
        cnt += __popc(bits);
    }
    red[tid] = cnt;
    __syncthreads();
    for (int s = 128; s; s >>= 1) {
        if (tid < s) red[tid] += red[tid + s];
        __syncthreads();
    }
    if (tid == 0) ws[OFF_MSUM + n] = red[0];
}

// One wave per (i,j), i<j: same class, both non-empty, boxes overlap ->
// popcount(mask_i & mask_j) written into the dense ovl table. PARALLEL —
// R6 showed serializing these into one wave costs ~50 us.
__global__ __launch_bounds__(64) void k_pairs(int* __restrict__ ws) {
    int i = blockIdx.x, j = blockIdx.y, tid = threadIdx.x;
    if (i >= j) return;
    if (ws[OFF_CLS + i] != ws[OFF_CLS + j]) return;
    if (ws[OFF_MSUM + i] == 0 || ws[OFF_MSUM + j] == 0) return;
    const int* bi = ws + OFF_BOX + 4 * i;
    const int* bj = ws + OFF_BOX + 4 * j;
    int ixs = max(bi[0], 0), ixe = min(bi[2] + 1, IMG);
    int iys = max(bi[1], 0), iye = min(bi[3] + 1, IMG);
    int jxs = max(bj[0], 0), jxe = min(bj[2] + 1, IMG);
    int jys = max(bj[1], 0), jye = min(bj[3] + 1, IMG);
    if (!(ixs < jxe && jxs < ixe && iys < jye && jys < iye)) return;
    int iwx0 = ixs >> 5, jwx0 = jxs >> 5;
    int wlo = max(iwx0, jwx0);
    int whi = min((ixe + 31) >> 5, (jxe + 31) >> 5);
    int rlo = max(iys, jys), rhi = min(iye, jye);
    int nw = whi - wlo, nrows = rhi - rlo;
    const unsigned* mi = (const unsigned*)(ws + OFF_MASK) + i * MSTRIDE;
    const unsigned* mj = (const unsigned*)(ws + OFF_MASK) + j * MSTRIDE;
    int total = nrows * nw, cnt = 0;
    for (int t = tid; t < total; t += 64) {
        int row = t / nw, wc = t - row * nw;
        int y = rlo + row, w = wlo + wc;
        cnt += __popc(mi[(y - iys) * ROWW + (w - iwx0)] &
                      mj[(y - jys) * ROWW + (w - jwx0)]);
    }
    for (int off = 32; off; off >>= 1) cnt += __shfl_down(cnt, off);
    if (tid == 0) ws[OFF_OVL + i * NINST + j] = cnt;
}

// Block 0: barrier-free wave scan (keep-bits in registers, O(1) dense-table
// lookups, bounds max<=|U|<=sum, rare exact-union fallback).
// Blocks [1,NZB]: stream the 256 MB output zero-fill, hiding the scan.
__global__ __launch_bounds__(256) void k_scan_zero(int* __restrict__ ws, float* __restrict__ out) {
    int b = blockIdx.x, tid = threadIdx.x;
    if (b > 0) { // zero path
        float4* outv = (float4*)(out + NINST);
        for (size_t pi = (size_t)(b - 1) * 256 + tid; pi < F4TOT; pi += (size_t)NZB * 256)
            outv[pi] = make_float4(0.f, 0.f, 0.f, 0.f);
        return;
    }
    __shared__ int s_ovl[NINST * NINST]; // 40 KB
    __shared__ int s_cls[NINST], s_msum[NINST], s_box[4 * NINST];
    for (int i = tid; i < NINST * NINST; i += 256) s_ovl[i] = ws[OFF_OVL + i];
    for (int i = tid; i < NINST; i += 256) {
        s_cls[i] = ws[OFF_CLS + i];
        s_msum[i] = ws[OFF_MSUM + i];
    }
    for (int i = tid; i < 4 * NINST; i += 256) s_box[i] = ws[OFF_BOX + i];
    __syncthreads();
    if (tid >= 64) return; // wave 0 only from here; no further barriers
    int ln = tid;
    const unsigned* maskbase = (const unsigned*)(ws + OFF_MASK);

    unsigned long long k0 = 0ull, k1 = 0ull; // replicated keep masks
    for (int n = 0; n < NINST; n++) {
        int msum = s_msum[n]; // uniform
        if (msum == 0) continue; // keep = 0
        int pb = 64 + ln;
        bool ca = (ln < n) && s_cls[ln] == s_cls[n] && ((k0 >> ln) & 1ull) && box_ovl(s_box, ln, n);
        bool cb = (pb < n) && s_cls[pb] == s_cls[n] && ((k1 >> ln) & 1ull) && box_ovl(s_box, pb, n);
        // guarded dense lookups: written by k_pairs under exactly these conditions
        int oa = ca ? s_ovl[ln * NINST + n] : 0;
        int ob = cb ? s_ovl[pb * NINST + n] : 0;
        int sum = oa + ob, mx = max(oa, ob);
        for (int off = 32; off; off >>= 1) {
            sum += __shfl_down(sum, off);
            mx = max(mx, __shfl_down(mx, off));
        }
        int keep = 0, need = 0;
        if (ln == 0) {
            float t = 0.3f * (float)msum;
            if ((float)sum <= t) keep = 1;      // ints exact in fp32; msum>0 known
            else if ((float)mx > t) keep = 0;   // single mask already exceeds
            else need = 1;                      // max <= t < sum: exact union
        }
        keep = __shfl(keep, 0);
        need = __shfl(need, 0);
        if (need) { // wave-cooperative exact union popcount (rare)
            unsigned long long ba = __ballot(ca), bb = __ballot(cb);
            int nxs = max(s_box[4 * n], 0), nxe = min(s_box[4 * n + 2] + 1, IMG);
            int nys = max(s_box[4 * n + 1], 0), nye = min(s_box[4 * n + 3] + 1, IMG);
            int wx0 = nxs >> 5, nw = ((nxe + 31) >> 5) - wx0, nrows = nye - nys;
            const unsigned* mn = maskbase + n * MSTRIDE;
            int total = nrows * nw, ovl = 0;
            for (int t2 = ln; t2 < total; t2 += 64) {
                int row = t2 / nw, wc = t2 - row * nw;
                unsigned bits = mn[row * ROWW + wc];
                if (!bits) continue;
                int y = nys + row, wa = wx0 + wc;
                unsigned img = 0;
                unsigned long long rem = ba;
                while (rem) {
                    int m = __ffsll((long long)rem) - 1; rem &= rem - 1;
                    int mys = max(s_box[4 * m + 1], 0), mye = min(s_box[4 * m + 3] + 1, IMG);
                    int mxs = max(s_box[4 * m], 0), mxe = min(s_box[4 * m + 2] + 1, IMG);
                    int mwx0 = mxs >> 5, mnw = ((mxe + 31) >> 5) - mwx0;
                    int rr = y - mys, cc = wa - mwx0;
                    if (rr >= 0 && rr < (mye - mys) && cc >= 0 && cc < mnw)
                        img |= maskbase[m * MSTRIDE + rr * ROWW + cc];
                }
                rem = bb;
                while (rem) {
                    int m0 = __ffsll((long long)rem) - 1; rem &= rem - 1;
                    int m = 64 + m0;
                    int mys = max(s_box[4 * m + 1], 0), mye = min(s_box[4 * m + 3] + 1, IMG);
                    int mxs = max(s_box[4 * m], 0), mxe = min(s_box[4 * m + 2] + 1, IMG);
                    int mwx0 = mxs >> 5, mnw = ((mxe + 31) >> 5) - mwx0;
                    int rr = y - mys, cc = wa - mwx0;
                    if (rr >= 0 && rr < (mye - mys) && cc >= 0 && cc < mnw)
                        img |= maskbase[m * MSTRIDE + rr * ROWW + cc];
                }
                ovl += __popc(bits & img);
            }
            for (int off = 32; off; off >>= 1) ovl += __shfl_down(ovl, off);
            if (ln == 0) keep = ((float)ovl <= 0.3f * (float)msum);
            keep = __shfl(keep, 0);
        }
        if (keep) { // uniform update of replicated keep masks
            if (n < 64) k0 |= 1ull << n;
            else k1 |= 1ull << (n - 64);
        }
    }

    // epilogue: slots + keep_inds (position = popcount of earlier keep bits)
    int nk = __popcll(k0) + __popcll(k1);
    if (ln == 0) ws[OFF_NK] = nk;
    unsigned long long lm = (ln == 0) ? 0ull : (~0ull >> (64 - ln));
    if ((k0 >> ln) & 1ull) {
        int pos = __popcll(k0 & lm);
        ws[OFF_SLOT + pos] = ln;
        out[pos] = (float)ws[OFF_ORDER + ln];
    }
    if (ln < 36 && ((k1 >> ln) & 1ull)) {
        int pos = __popcll(k0) + __popcll(k1 & lm);
        ws[OFF_SLOT + pos] = 64 + ln;
        out[pos] = (float)ws[OFF_ORDER + 64 + ln];
    }
    for (int s = ln; s < NINST; s += 64)
        if (s >= nk) out[s] = -1.f;
}

// Writes kept boxes' interiors only (~33 MB; rest already zeroed).
__global__ __launch_bounds__(256) void k_box(const float* __restrict__ mask_prob,
                                             const int* __restrict__ ws,
                                             float* __restrict__ out) {
    int slot = blockIdx.y, tid = threadIdx.x;
    if (slot >= ws[OFF_NK]) return; // uniform per block
    int n = ws[OFF_SLOT + slot];
    const int* box = ws + OFF_BOX + 4 * n;
    int x0 = box[0], y0 = box[1], x1 = box[2], y1 = box[3];
    int xs = max(x0, 0), xe = min(x1 + 1, IMG);
    int ys = max(y0, 0), ye = min(y1 + 1, IMG);
    int xa = xs & ~3;
    int w4 = (xe - xa + 3) >> 2;
    int rows = ye - ys;
    int total4 = rows * w4;
    __shared__ float lg[LOGSZ];
    int orig = ws[OFF_ORDER + n];
    for (int i = tid; i < LOGSZ; i += 256) lg[i] = mask_prob[orig * LOGSZ + i];
    __syncthreads();
    float wf = fmaxf((float)(x1 - x0 + 1), 1.f), hf = fmaxf((float)(y1 - y0 + 1), 1.f);
    float rx = 28.f / wf, ry = 28.f / hf;
    float* base = out + NINST + (size_t)slot * (IMG * IMG);
    for (int t = blockIdx.x * 256 + tid; t < total4; t += gridDim.x * 256) {
        int row = t / w4, c4 = t - row * w4;
        int y = ys + row, xb = xa + (c4 << 2);
        float sy = ((float)y - (float)y0 + 0.5f) * ry - 0.5f;
        sy = fminf(fmaxf(sy, 0.f), 27.f);
        int iy0 = (int)sy, iy1 = min(iy0 + 1, 27);
        float fy = sy - (float)iy0;
        const float* r0 = lg + iy0 * MLOG;
        const float* r1 = lg + iy1 * MLOG;
        float v[4];
#pragma unroll
        for (int j = 0; j < 4; j++) {
            int xx = xb + j;
            float val = 0.f;
            if (xx >= xs && xx < xe) {
                float sx = ((float)xx - (float)x0 + 0.5f) * rx - 0.5f;
                sx = fminf(fmaxf(sx, 0.f), 27.f);
                int ix0 = (int)sx, ix1 = min(ix0 + 1, 27);
                float fx = sx - (float)ix0;
                val = (1.f - fy) * ((1.f - fx) * r0[ix0] + fx * r0[ix1]) +
                      fy * ((1.f - fx) * r1[ix0] + fx * r1[ix1]);
            }
            v[j] = val;
        }
        *(float4*)(base + (size_t)y * IMG + xb) = make_float4(v[0], v[1], v[2], v[3]);
    }
}

extern "C" void kernel_launch(void* const* d_in, const int* in_sizes, int n_in,
                              void* d_out, int out_size, void* d_ws, size_t ws_size,
                              hipStream_t stream) {
    const float* rois      = (const float*)d_in[0];
    const float* cls_prob  = (const float*)d_in[1];
    const float* mask_prob = (const float*)d_in[2];
    const int*   cls_idx   = (const int*)d_in[3];
    int* ws = (int*)d_ws;
    float* out = (float*)d_out;

    k_mask<<<dim3(NINST), dim3(256), 0, stream>>>(mask_prob, cls_prob, rois, cls_idx, ws);
    k_pairs<<<dim3(NINST, NINST), dim3(64), 0, stream>>>(ws);
    k_scan_zero<<<dim3(NZB + 1), dim3(256), 0, stream>>>(ws, out);
    // max box 301x301 -> rows*w4 <= 301*77 = 23177 <= 91*256
    k_box<<<dim3(91, NINST), dim3(256), 0, stream>>>(mask_prob, ws, out);
}